// Round 1
// baseline (405.180 us; speedup 1.0000x reference)
//
#include <hip/hip_runtime.h>

typedef __attribute__((ext_vector_type(8))) short short8;
typedef __attribute__((ext_vector_type(4))) float f32x4;

static __device__ __forceinline__ short f2bf(float x) {
  union { float f; unsigned u; } v; v.f = x;
  unsigned r = (v.u + 0x7fffu + ((v.u >> 16) & 1u)) >> 16;
  return (short)r;
}

__global__ __launch_bounds__(256) void convert_f32_bf16(const float* __restrict__ src,
                                                        short* __restrict__ dst, int n8) {
  int i = blockIdx.x * 256 + threadIdx.x;
  if (i >= n8) return;
  const f32x4* s = (const f32x4*)(src + (long)i * 8);
  f32x4 a = s[0], b = s[1];
  short8 o;
  o[0] = f2bf(a[0]); o[1] = f2bf(a[1]); o[2] = f2bf(a[2]); o[3] = f2bf(a[3]);
  o[4] = f2bf(b[0]); o[5] = f2bf(b[1]); o[6] = f2bf(b[2]); o[7] = f2bf(b[3]);
  *(short8*)(dst + (long)i * 8) = o;
}

// C[M,N] = scale * A[M,K] @ B[N,K]^T + bias + resid.
// A: bf16 (ws) or f32 (AF32). B: bf16, row-major [N][K] (i.e. B^T form, K contiguous).
// OMODE 0: C[row*ldc + col*cstride]; OMODE 1: vt store C[(row>>10)<<20 | col<<10 | row&1023].
// blockIdx.z: batch; z = zb*16 + zg (strides sXb/sXg); pass 0 strides for Z=1.
template <int BM, int BN, int BK, bool AF32, int OMODE, typename OutT>
__global__ __launch_bounds__(256) void gemm_mfma(
    const void* __restrict__ Abase, int lda, long sAb, long sAg,
    const short* __restrict__ Bbase, int ldb, long sBb, long sBg,
    OutT* __restrict__ Cbase, int ldc, int cstride, long sCb, long sCg,
    const float* __restrict__ bias,
    const float* __restrict__ resid, int ldres,
    float scale, int K) {
  constexpr int WN = (BN >= 128) ? 2 : 1;
  constexpr int WM = 4 / WN;
  constexpr int WTM = BM / WM;
  constexpr int WTN = BN / WN;
  constexpr int MF = WTM / 16;
  constexpr int NF = WTN / 16;
  constexpr int PAD = 8;                 // 40-short row stride: 16B aligned, ~2-way banks
  constexpr int LDK = BK + PAD;
  constexpr int TPR = BK / 8;            // threads per staged row
  constexpr int RPI = 256 / TPR;         // rows per staging iteration
  constexpr int AIT = BM / RPI;
  constexpr int BIT = BN / RPI;

  __shared__ short As[BM * LDK];
  __shared__ short Bs[BN * LDK];

  const int z = blockIdx.z;
  const int zb = z >> 4, zg = z & 15;
  const int bm = blockIdx.y * BM, bn = blockIdx.x * BN;
  const int tid = threadIdx.x, lane = tid & 63, wave = tid >> 6;
  const int wr = wave / WN, wc = wave % WN;
  const int srow = tid / TPR, scol = (tid % TPR) * 8;

  const short* Bp = Bbase + zb * sBb + zg * sBg;
  const short* A16 = AF32 ? nullptr : ((const short*)Abase + zb * sAb + zg * sAg);
  const float* A32 = AF32 ? ((const float*)Abase + zb * sAb + zg * sAg) : nullptr;

  f32x4 acc[MF][NF];
#pragma unroll
  for (int m = 0; m < MF; ++m)
#pragma unroll
    for (int n = 0; n < NF; ++n) acc[m][n] = (f32x4){0.f, 0.f, 0.f, 0.f};

  for (int k0 = 0; k0 < K; k0 += BK) {
#pragma unroll
    for (int it = 0; it < AIT; ++it) {
      int r = it * RPI + srow;
      if (!AF32) {
        *(short8*)&As[r * LDK + scol] =
            *(const short8*)(A16 + (long)(bm + r) * lda + k0 + scol);
      } else {
        const float* p = A32 + (long)(bm + r) * lda + k0 + scol;
        f32x4 x = *(const f32x4*)p, y = *(const f32x4*)(p + 4);
        short8 o;
        o[0] = f2bf(x[0]); o[1] = f2bf(x[1]); o[2] = f2bf(x[2]); o[3] = f2bf(x[3]);
        o[4] = f2bf(y[0]); o[5] = f2bf(y[1]); o[6] = f2bf(y[2]); o[7] = f2bf(y[3]);
        *(short8*)&As[r * LDK + scol] = o;
      }
    }
#pragma unroll
    for (int it = 0; it < BIT; ++it) {
      int r = it * RPI + srow;
      *(short8*)&Bs[r * LDK + scol] =
          *(const short8*)(Bp + (long)(bn + r) * ldb + k0 + scol);
    }
    __syncthreads();
#pragma unroll
    for (int ks = 0; ks < BK; ks += 32) {
      short8 af[MF], bf[NF];
#pragma unroll
      for (int m = 0; m < MF; ++m)
        af[m] = *(const short8*)&As[(wr * WTM + m * 16 + (lane & 15)) * LDK + ks +
                                    (lane >> 4) * 8];
#pragma unroll
      for (int n = 0; n < NF; ++n)
        bf[n] = *(const short8*)&Bs[(wc * WTN + n * 16 + (lane & 15)) * LDK + ks +
                                    (lane >> 4) * 8];
#pragma unroll
      for (int m = 0; m < MF; ++m)
#pragma unroll
        for (int n = 0; n < NF; ++n)
          acc[m][n] = __builtin_amdgcn_mfma_f32_16x16x32_bf16(af[m], bf[n], acc[m][n], 0, 0, 0);
    }
    __syncthreads();
  }

  OutT* C = Cbase + zb * sCb + zg * sCg;
  const int col0 = lane & 15, row0 = (lane >> 4) * 4;
#pragma unroll
  for (int m = 0; m < MF; ++m) {
#pragma unroll
    for (int n = 0; n < NF; ++n) {
      int gcol = bn + wc * WTN + n * 16 + col0;
      float bi = bias ? bias[gcol] : 0.f;
#pragma unroll
      for (int i = 0; i < 4; ++i) {
        int grow = bm + wr * WTM + m * 16 + row0 + i;
        float v = acc[m][n][i] * scale + bi;
        if (resid) v += resid[(long)grow * ldres + gcol];
        long addr;
        if (OMODE == 0)
          addr = (long)grow * ldc + (long)gcol * cstride;
        else
          addr = ((long)(grow >> 10) << 20) + ((long)gcol << 10) + (grow & 1023);
        if constexpr (sizeof(OutT) == 2)
          C[addr] = (OutT)f2bf(v);
        else
          C[addr] = v;
      }
    }
  }
}

// one wave per 1024-elem row, in place
__global__ __launch_bounds__(256) void softmax_rows(float* __restrict__ P) {
  const int row = blockIdx.x * 4 + (threadIdx.x >> 6);
  const int lane = threadIdx.x & 63;
  float* p = P + (long)row * 1024 + lane * 4;
  f32x4 v[4];
  float m = -3.4e38f;
#pragma unroll
  for (int j = 0; j < 4; ++j) {
    v[j] = *(const f32x4*)(p + j * 256);
    m = fmaxf(m, fmaxf(fmaxf(v[j][0], v[j][1]), fmaxf(v[j][2], v[j][3])));
  }
#pragma unroll
  for (int off = 32; off; off >>= 1) m = fmaxf(m, __shfl_xor(m, off));
  float s = 0.f;
#pragma unroll
  for (int j = 0; j < 4; ++j) {
    v[j][0] = __expf(v[j][0] - m);
    v[j][1] = __expf(v[j][1] - m);
    v[j][2] = __expf(v[j][2] - m);
    v[j][3] = __expf(v[j][3] - m);
    s += v[j][0] + v[j][1] + v[j][2] + v[j][3];
  }
#pragma unroll
  for (int off = 32; off; off >>= 1) s += __shfl_xor(s, off);
  const float inv = 1.f / s;
#pragma unroll
  for (int j = 0; j < 4; ++j) {
    v[j] *= inv;
    *(f32x4*)(p + j * 256) = v[j];
  }
}

// one wave per 1024-elem row
__global__ __launch_bounds__(256) void layernorm_rows(const float* __restrict__ X,
                                                      const float* __restrict__ gamma,
                                                      const float* __restrict__ beta,
                                                      float* __restrict__ O) {
  const int row = blockIdx.x * 4 + (threadIdx.x >> 6);
  const int lane = threadIdx.x & 63;
  const float* x = X + (long)row * 1024 + lane * 4;
  f32x4 v[4];
  float s = 0.f, sq = 0.f;
#pragma unroll
  for (int j = 0; j < 4; ++j) {
    v[j] = *(const f32x4*)(x + j * 256);
#pragma unroll
    for (int e = 0; e < 4; ++e) {
      s += v[j][e];
      sq += v[j][e] * v[j][e];
    }
  }
#pragma unroll
  for (int off = 32; off; off >>= 1) {
    s += __shfl_xor(s, off);
    sq += __shfl_xor(sq, off);
  }
  const float mu = s * (1.f / 1024.f);
  const float var = sq * (1.f / 1024.f) - mu * mu;
  const float rstd = rsqrtf(var + 1e-5f);
  float* o = O + (long)row * 1024 + lane * 4;
#pragma unroll
  for (int j = 0; j < 4; ++j) {
    f32x4 g = *(const f32x4*)(gamma + lane * 4 + j * 256);
    f32x4 be = *(const f32x4*)(beta + lane * 4 + j * 256);
    f32x4 r;
#pragma unroll
    for (int e = 0; e < 4; ++e) r[e] = (v[j][e] - mu) * rstd * g[e] + be[e];
    *(f32x4*)(o + j * 256) = r;
  }
}

extern "C" void kernel_launch(void* const* d_in, const int* in_sizes, int n_in,
                              void* d_out, int out_size, void* d_ws, size_t ws_size,
                              hipStream_t stream) {
  const float* Q = (const float*)d_in[0];
  const float* KV = (const float*)d_in[1];
  const float* Wq = (const float*)d_in[2];
  const float* bq = (const float*)d_in[3];
  const float* Wk = (const float*)d_in[4];
  const float* bk = (const float*)d_in[5];
  const float* Wv = (const float*)d_in[6];
  const float* bv = (const float*)d_in[7];
  const float* Wp = (const float*)d_in[8];
  const float* bp = (const float*)d_in[9];
  const float* gamma = (const float*)d_in[10];
  const float* beta = (const float*)d_in[11];

  float* out = (float*)d_out;                       // [4M] f32
  float* scores = out + (long)4 * 1024 * 1024;      // [64M] f32

  char* ws = (char*)d_ws;
  short* at = (short*)(ws);                         // attnflat bf16, 8MB (reuses conv space later)
  float* pre = (float*)(ws + (8L << 20));           // pre-LN f32, 16MB
  short* Qb = (short*)(ws);                         // 8MB (dead after proj-q)
  short* KVb = (short*)(ws + (8L << 20));           // 8MB (dead after proj-v)
  short* Wqb = (short*)(ws + (16L << 20));          // 2MB each
  short* Wkb = (short*)(ws + (18L << 20));
  short* Wvb = (short*)(ws + (20L << 20));
  short* Wpb = (short*)(ws + (22L << 20));
  short* qb = (short*)(ws + (24L << 20));           // 8MB
  short* kb = (short*)(ws + (32L << 20));           // 8MB
  short* vt = (short*)(ws + (40L << 20));           // 8MB  -> peak 48MB
  (void)ws_size; (void)in_sizes; (void)n_in; (void)out_size;

  // Note: at/pre overlap Qb/KVb: Qb dead after proj-q, KVb dead after proj-v,
  // and at/pre are first written by PV / final GEMM which run after those.
  // But Wpb (22-24MB) must survive until final GEMM: pre spans 8-24MB -> conflict!
  // Fix: move pre past vt.
  pre = (float*)(ws + (48L << 20));                 // 16MB -> peak 64MB

  const long M1 = 1048576;

  // 1) f32 -> bf16 conversions
  convert_f32_bf16<<<2048, 256, 0, stream>>>(Q, Qb, 524288);
  convert_f32_bf16<<<2048, 256, 0, stream>>>(KV, KVb, 524288);
  convert_f32_bf16<<<512, 256, 0, stream>>>(Wq, Wqb, 131072);
  convert_f32_bf16<<<512, 256, 0, stream>>>(Wk, Wkb, 131072);
  convert_f32_bf16<<<512, 256, 0, stream>>>(Wv, Wvb, 131072);
  convert_f32_bf16<<<512, 256, 0, stream>>>(Wp, Wpb, 131072);

  // 2) projections: q = Qb@Wq^T+bq (bf16), k = KVb@Wk^T+bk (bf16), v -> vt transposed
  gemm_mfma<128, 128, 32, false, 0, short><<<dim3(8, 32, 1), 256, 0, stream>>>(
      Qb, 1024, 0, 0, Wqb, 1024, 0, 0, qb, 1024, 1, 0, 0, bq, nullptr, 0, 1.f, 1024);
  gemm_mfma<128, 128, 32, false, 0, short><<<dim3(8, 32, 1), 256, 0, stream>>>(
      KVb, 1024, 0, 0, Wkb, 1024, 0, 0, kb, 1024, 1, 0, 0, bk, nullptr, 0, 1.f, 1024);
  gemm_mfma<128, 128, 32, false, 1, short><<<dim3(8, 32, 1), 256, 0, stream>>>(
      KVb, 1024, 0, 0, Wvb, 1024, 0, 0, vt, 1024, 1, 0, 0, bv, nullptr, 0, 1.f, 1024);

  // 3) logits[z=b*16+g][s][t] = 0.125 * q_g @ k_g^T   (raw, f32, into scores region)
  gemm_mfma<128, 128, 32, false, 0, float><<<dim3(8, 8, 64), 256, 0, stream>>>(
      qb, 1024, M1, 64, kb, 1024, M1, 64, scores, 1024, 1, 16 * M1, M1,
      nullptr, nullptr, 0, 0.125f, 64);

  // 4) softmax rows in place (65536 rows)
  softmax_rows<<<16384, 256, 0, stream>>>(scores);

  // 5) attnflat[b][s][d*16+g] = P_g @ Vg   (A = f32 scores, B = vt)
  gemm_mfma<128, 64, 32, true, 0, short><<<dim3(1, 8, 64), 256, 0, stream>>>(
      scores, 1024, 16 * M1, M1, vt, 16384, M1, 1024, at, 1024, 16, M1, 1,
      nullptr, nullptr, 0, 1.f, 1024);

  // 6) pre = at@Wp^T + bp + Q
  gemm_mfma<128, 128, 32, false, 0, float><<<dim3(8, 32, 1), 256, 0, stream>>>(
      at, 1024, 0, 0, Wpb, 1024, 0, 0, pre, 1024, 1, 0, 0, bp, Q, 1024, 1.f, 1024);

  // 7) LayerNorm -> out
  layernorm_rows<<<1024, 256, 0, stream>>>(pre, gamma, beta, out);
}

// Round 2
// 339.150 us; speedup vs baseline: 1.1947x; 1.1947x over previous
//
#include <hip/hip_runtime.h>

typedef __attribute__((ext_vector_type(8))) short short8;
typedef __attribute__((ext_vector_type(4))) float f32x4;

static __device__ __forceinline__ short f2bf(float x) {
  union { float f; unsigned u; } v; v.f = x;
  unsigned r = (v.u + 0x7fffu + ((v.u >> 16) & 1u)) >> 16;
  return (short)r;
}

__global__ __launch_bounds__(256) void convert_f32_bf16(const float* __restrict__ src,
                                                        short* __restrict__ dst, int n8) {
  int i = blockIdx.x * 256 + threadIdx.x;
  if (i >= n8) return;
  const f32x4* s = (const f32x4*)(src + (long)i * 8);
  f32x4 a = s[0], b = s[1];
  short8 o;
  o[0] = f2bf(a[0]); o[1] = f2bf(a[1]); o[2] = f2bf(a[2]); o[3] = f2bf(a[3]);
  o[4] = f2bf(b[0]); o[5] = f2bf(b[1]); o[6] = f2bf(b[2]); o[7] = f2bf(b[3]);
  *(short8*)(dst + (long)i * 8) = o;
}

// C[M,N] = scale * A[M,K] @ B[N,K]^T + bias + resid.
// OMODE 0: C[row*ldc + col*cstride]; OMODE 1: vt store C[(row>>10)<<20 | col<<10 | row&1023].
template <int BM, int BN, int BK, int OMODE, typename OutT>
__global__ __launch_bounds__(256) void gemm_mfma(
    const short* __restrict__ Abase, int lda,
    const short* __restrict__ Bbase, int ldb,
    OutT* __restrict__ Cbase, int ldc, int cstride,
    const float* __restrict__ bias,
    const float* __restrict__ resid, int ldres,
    float scale, int K) {
  constexpr int WN = (BN >= 128) ? 2 : 1;
  constexpr int WM = 4 / WN;
  constexpr int WTM = BM / WM;
  constexpr int WTN = BN / WN;
  constexpr int MF = WTM / 16;
  constexpr int NF = WTN / 16;
  constexpr int PAD = 8;
  constexpr int LDK = BK + PAD;
  constexpr int TPR = BK / 8;
  constexpr int RPI = 256 / TPR;
  constexpr int AIT = BM / RPI;
  constexpr int BIT = BN / RPI;

  __shared__ short As[BM * LDK];
  __shared__ short Bs[BN * LDK];

  const int bm = blockIdx.y * BM, bn = blockIdx.x * BN;
  const int tid = threadIdx.x, lane = tid & 63, wave = tid >> 6;
  const int wr = wave / WN, wc = wave % WN;
  const int srow = tid / TPR, scol = (tid % TPR) * 8;

  f32x4 acc[MF][NF];
#pragma unroll
  for (int m = 0; m < MF; ++m)
#pragma unroll
    for (int n = 0; n < NF; ++n) acc[m][n] = (f32x4){0.f, 0.f, 0.f, 0.f};

  for (int k0 = 0; k0 < K; k0 += BK) {
#pragma unroll
    for (int it = 0; it < AIT; ++it) {
      int r = it * RPI + srow;
      *(short8*)&As[r * LDK + scol] =
          *(const short8*)(Abase + (long)(bm + r) * lda + k0 + scol);
    }
#pragma unroll
    for (int it = 0; it < BIT; ++it) {
      int r = it * RPI + srow;
      *(short8*)&Bs[r * LDK + scol] =
          *(const short8*)(Bbase + (long)(bn + r) * ldb + k0 + scol);
    }
    __syncthreads();
#pragma unroll
    for (int ks = 0; ks < BK; ks += 32) {
      short8 af[MF], bf[NF];
#pragma unroll
      for (int m = 0; m < MF; ++m)
        af[m] = *(const short8*)&As[(wr * WTM + m * 16 + (lane & 15)) * LDK + ks +
                                    (lane >> 4) * 8];
#pragma unroll
      for (int n = 0; n < NF; ++n)
        bf[n] = *(const short8*)&Bs[(wc * WTN + n * 16 + (lane & 15)) * LDK + ks +
                                    (lane >> 4) * 8];
#pragma unroll
      for (int m = 0; m < MF; ++m)
#pragma unroll
        for (int n = 0; n < NF; ++n)
          acc[m][n] = __builtin_amdgcn_mfma_f32_16x16x32_bf16(af[m], bf[n], acc[m][n], 0, 0, 0);
    }
    __syncthreads();
  }

  const int col0 = lane & 15, row0 = (lane >> 4) * 4;
#pragma unroll
  for (int m = 0; m < MF; ++m) {
#pragma unroll
    for (int n = 0; n < NF; ++n) {
      int gcol = bn + wc * WTN + n * 16 + col0;
      float bi = bias ? bias[gcol] : 0.f;
#pragma unroll
      for (int i = 0; i < 4; ++i) {
        int grow = bm + wr * WTM + m * 16 + row0 + i;
        float v = acc[m][n][i] * scale + bi;
        if (resid) v += resid[(long)grow * ldres + gcol];
        long addr;
        if (OMODE == 0)
          addr = (long)grow * ldc + (long)gcol * cstride;
        else
          addr = ((long)(grow >> 10) << 20) + ((long)gcol << 10) + (grow & 1023);
        if constexpr (sizeof(OutT) == 2)
          Cbase[addr] = (OutT)f2bf(v);
        else
          Cbase[addr] = v;
      }
    }
  }
}

// Fused attention: per block (z = b*16+g, 64 q-rows): two-pass online softmax with
// QK^T recompute; writes normalized scores (f32, mandatory output) and attnflat bf16.
__global__ __launch_bounds__(256) void fused_attn(
    const short* __restrict__ qb,   // [4][1024][1024] bf16, feat = g*64+d
    const short* __restrict__ kb,   // [4][1024][1024] bf16, feat = g*64+d
    const short* __restrict__ vt,   // [4][1024][1024] bf16, vt[b][d*16+g][t]
    float* __restrict__ scores,     // [64][1024][1024] f32
    short* __restrict__ at) {       // [4][1024][1024] bf16, feat = d*16+g
  constexpr int LK = 72;   // K tile LDS stride (shorts): 144B -> 4-bank step, <=2-way
  constexpr int LP = 136;  // P tile LDS stride: 272B -> 4-bank step, <=2-way
  __shared__ short Ks[128 * LK];
  __shared__ short Ps[64 * LP];

  const int z = blockIdx.y, b = z >> 4, g = z & 15;
  const int q0 = blockIdx.x * 64;
  const int tid = threadIdx.x, lane = tid & 63, w = tid >> 6;
  const int fr = lane & 15, khi = lane >> 4;
  const long bqk = (long)b << 20;

  // Q fragments: 16 rows per wave, each lane holds 2 short8 (whole-kernel lifetime)
  const short* qrow = qb + bqk + (long)(q0 + w * 16 + fr) * 1024 + g * 64 + khi * 8;
  short8 aq0 = *(const short8*)qrow;
  short8 aq1 = *(const short8*)(qrow + 32);

  const int sr = tid >> 3, sc = (tid & 7) * 8;

  float m4[4] = {-3.4e38f, -3.4e38f, -3.4e38f, -3.4e38f};
  float s4[4] = {0.f, 0.f, 0.f, 0.f};

  // ---- pass 1: online max+sum over all key tiles ----
  for (int t0 = 0; t0 < 1024; t0 += 128) {
#pragma unroll
    for (int it = 0; it < 4; ++it) {
      int row = it * 32 + sr;
      *(short8*)&Ks[row * LK + sc] =
          *(const short8*)(kb + bqk + (long)(t0 + row) * 1024 + g * 64 + sc);
    }
    __syncthreads();
    f32x4 sacc[8];
#pragma unroll
    for (int nf = 0; nf < 8; ++nf) sacc[nf] = (f32x4){0.f, 0.f, 0.f, 0.f};
#pragma unroll
    for (int nf = 0; nf < 8; ++nf) {
      short8 b0 = *(const short8*)&Ks[(nf * 16 + fr) * LK + khi * 8];
      short8 b1 = *(const short8*)&Ks[(nf * 16 + fr) * LK + 32 + khi * 8];
      sacc[nf] = __builtin_amdgcn_mfma_f32_16x16x32_bf16(aq0, b0, sacc[nf], 0, 0, 0);
      sacc[nf] = __builtin_amdgcn_mfma_f32_16x16x32_bf16(aq1, b1, sacc[nf], 0, 0, 0);
    }
#pragma unroll
    for (int i = 0; i < 4; ++i) {
      float tm = sacc[0][i];
#pragma unroll
      for (int nf = 1; nf < 8; ++nf) tm = fmaxf(tm, sacc[nf][i]);
      tm *= 0.125f;
      tm = fmaxf(tm, __shfl_xor(tm, 1));
      tm = fmaxf(tm, __shfl_xor(tm, 2));
      tm = fmaxf(tm, __shfl_xor(tm, 4));
      tm = fmaxf(tm, __shfl_xor(tm, 8));
      float mn = fmaxf(m4[i], tm);
      float te = 0.f;
#pragma unroll
      for (int nf = 0; nf < 8; ++nf) te += __expf(sacc[nf][i] * 0.125f - mn);
      te += __shfl_xor(te, 1);
      te += __shfl_xor(te, 2);
      te += __shfl_xor(te, 4);
      te += __shfl_xor(te, 8);
      s4[i] = s4[i] * __expf(m4[i] - mn) + te;
      m4[i] = mn;
    }
    __syncthreads();
  }

  float inv4[4];
#pragma unroll
  for (int i = 0; i < 4; ++i) inv4[i] = 1.f / s4[i];

  f32x4 pacc[4];
#pragma unroll
  for (int nv = 0; nv < 4; ++nv) pacc[nv] = (f32x4){0.f, 0.f, 0.f, 0.f};

  // ---- pass 2: recompute, write scores, accumulate PV ----
  for (int t0 = 0; t0 < 1024; t0 += 128) {
#pragma unroll
    for (int it = 0; it < 4; ++it) {
      int row = it * 32 + sr;
      *(short8*)&Ks[row * LK + sc] =
          *(const short8*)(kb + bqk + (long)(t0 + row) * 1024 + g * 64 + sc);
    }
    __syncthreads();
    f32x4 sacc[8];
#pragma unroll
    for (int nf = 0; nf < 8; ++nf) sacc[nf] = (f32x4){0.f, 0.f, 0.f, 0.f};
#pragma unroll
    for (int nf = 0; nf < 8; ++nf) {
      short8 b0 = *(const short8*)&Ks[(nf * 16 + fr) * LK + khi * 8];
      short8 b1 = *(const short8*)&Ks[(nf * 16 + fr) * LK + 32 + khi * 8];
      sacc[nf] = __builtin_amdgcn_mfma_f32_16x16x32_bf16(aq0, b0, sacc[nf], 0, 0, 0);
      sacc[nf] = __builtin_amdgcn_mfma_f32_16x16x32_bf16(aq1, b1, sacc[nf], 0, 0, 0);
    }
#pragma unroll
    for (int nf = 0; nf < 8; ++nf) {
#pragma unroll
      for (int i = 0; i < 4; ++i) {
        float p = __expf(sacc[nf][i] * 0.125f - m4[i]) * inv4[i];
        scores[((long)z << 20) + ((long)(q0 + w * 16 + khi * 4 + i) << 10) + t0 +
               nf * 16 + fr] = p;
        Ps[(w * 16 + khi * 4 + i) * LP + nf * 16 + fr] = f2bf(p);
      }
    }
    // PV: Ps rows are wave-private; V fragments straight from L2-resident vt
#pragma unroll
    for (int ks = 0; ks < 128; ks += 32) {
      short8 ap = *(const short8*)&Ps[(w * 16 + fr) * LP + ks + khi * 8];
#pragma unroll
      for (int nv = 0; nv < 4; ++nv) {
        short8 bv = *(const short8*)(vt + bqk +
                                     ((long)((nv * 16 + fr) * 16 + g) << 10) + t0 + ks +
                                     khi * 8);
        pacc[nv] = __builtin_amdgcn_mfma_f32_16x16x32_bf16(ap, bv, pacc[nv], 0, 0, 0);
      }
    }
    __syncthreads();
  }

#pragma unroll
  for (int nv = 0; nv < 4; ++nv)
#pragma unroll
    for (int i = 0; i < 4; ++i)
      at[bqk + ((long)(q0 + w * 16 + khi * 4 + i) << 10) + (nv * 16 + fr) * 16 + g] =
          f2bf(pacc[nv][i]);
}

// one wave per 1024-elem row
__global__ __launch_bounds__(256) void layernorm_rows(const float* __restrict__ X,
                                                      const float* __restrict__ gamma,
                                                      const float* __restrict__ beta,
                                                      float* __restrict__ O) {
  const int row = blockIdx.x * 4 + (threadIdx.x >> 6);
  const int lane = threadIdx.x & 63;
  const float* x = X + (long)row * 1024 + lane * 4;
  f32x4 v[4];
  float s = 0.f, sq = 0.f;
#pragma unroll
  for (int j = 0; j < 4; ++j) {
    v[j] = *(const f32x4*)(x + j * 256);
#pragma unroll
    for (int e = 0; e < 4; ++e) {
      s += v[j][e];
      sq += v[j][e] * v[j][e];
    }
  }
#pragma unroll
  for (int off = 32; off; off >>= 1) {
    s += __shfl_xor(s, off);
    sq += __shfl_xor(sq, off);
  }
  const float mu = s * (1.f / 1024.f);
  const float var = sq * (1.f / 1024.f) - mu * mu;
  const float rstd = rsqrtf(var + 1e-5f);
  float* o = O + (long)row * 1024 + lane * 4;
#pragma unroll
  for (int j = 0; j < 4; ++j) {
    f32x4 g = *(const f32x4*)(gamma + lane * 4 + j * 256);
    f32x4 be = *(const f32x4*)(beta + lane * 4 + j * 256);
    f32x4 r;
#pragma unroll
    for (int e = 0; e < 4; ++e) r[e] = (v[j][e] - mu) * rstd * g[e] + be[e];
    *(f32x4*)(o + j * 256) = r;
  }
}

extern "C" void kernel_launch(void* const* d_in, const int* in_sizes, int n_in,
                              void* d_out, int out_size, void* d_ws, size_t ws_size,
                              hipStream_t stream) {
  const float* Q = (const float*)d_in[0];
  const float* KV = (const float*)d_in[1];
  const float* Wq = (const float*)d_in[2];
  const float* bq = (const float*)d_in[3];
  const float* Wk = (const float*)d_in[4];
  const float* bk = (const float*)d_in[5];
  const float* Wv = (const float*)d_in[6];
  const float* bv = (const float*)d_in[7];
  const float* Wp = (const float*)d_in[8];
  const float* bp = (const float*)d_in[9];
  const float* gamma = (const float*)d_in[10];
  const float* beta = (const float*)d_in[11];

  float* out = (float*)d_out;                       // [4M] f32
  float* scores = out + (long)4 * 1024 * 1024;      // [64M] f32

  char* ws = (char*)d_ws;
  short* at = (short*)(ws);                         // 8MB (overlaps Qb, dead by then)
  short* Qb = (short*)(ws);                         // 8MB
  short* KVb = (short*)(ws + (8L << 20));           // 8MB
  short* Wqb = (short*)(ws + (16L << 20));          // 2MB each
  short* Wkb = (short*)(ws + (18L << 20));
  short* Wvb = (short*)(ws + (20L << 20));
  short* Wpb = (short*)(ws + (22L << 20));
  short* qb = (short*)(ws + (24L << 20));           // 8MB
  short* kb = (short*)(ws + (32L << 20));           // 8MB
  short* vt = (short*)(ws + (40L << 20));           // 8MB
  float* pre = (float*)(ws + (48L << 20));          // 16MB -> peak 64MB
  (void)ws_size; (void)in_sizes; (void)n_in; (void)out_size;

  // 1) f32 -> bf16 conversions
  convert_f32_bf16<<<2048, 256, 0, stream>>>(Q, Qb, 524288);
  convert_f32_bf16<<<2048, 256, 0, stream>>>(KV, KVb, 524288);
  convert_f32_bf16<<<512, 256, 0, stream>>>(Wq, Wqb, 131072);
  convert_f32_bf16<<<512, 256, 0, stream>>>(Wk, Wkb, 131072);
  convert_f32_bf16<<<512, 256, 0, stream>>>(Wv, Wvb, 131072);
  convert_f32_bf16<<<512, 256, 0, stream>>>(Wp, Wpb, 131072);

  // 2) projections
  gemm_mfma<128, 128, 32, 0, short><<<dim3(8, 32, 1), 256, 0, stream>>>(
      Qb, 1024, Wqb, 1024, qb, 1024, 1, bq, nullptr, 0, 1.f, 1024);
  gemm_mfma<128, 128, 32, 0, short><<<dim3(8, 32, 1), 256, 0, stream>>>(
      KVb, 1024, Wkb, 1024, kb, 1024, 1, bk, nullptr, 0, 1.f, 1024);
  gemm_mfma<128, 128, 32, 1, short><<<dim3(8, 32, 1), 256, 0, stream>>>(
      KVb, 1024, Wvb, 1024, vt, 1024, 1, bv, nullptr, 0, 1.f, 1024);

  // 3) fused logits+softmax+PV: writes scores (d_out) and at (bf16)
  fused_attn<<<dim3(16, 64), 256, 0, stream>>>(qb, kb, vt, scores, at);

  // 4) pre = at@Wp^T + bp + Q
  gemm_mfma<128, 128, 32, 0, float><<<dim3(8, 32, 1), 256, 0, stream>>>(
      at, 1024, Wpb, 1024, pre, 1024, 1, bp, Q, 1024, 1.f, 1024);

  // 5) LayerNorm -> out
  layernorm_rows<<<1024, 256, 0, stream>>>(pre, gamma, beta, out);
}